// Round 1
// baseline (7004.253 us; speedup 1.0000x reference)
//
#include <hip/hip_runtime.h>
#include <hip/hip_fp16.h>

// ---------------------------------------------------------------------------
// LSTM position predictor, persistent cooperative kernel.
//   H=2048, B=64, T=128 enc steps, 64 dec steps.
//   - 256 blocks x 512 threads, 1 block/CU (LDS-bound), custom grid barrier.
//   - Whh weights converted fp32->fp16 and held PERSISTENT in LDS
//     (32 gate-rows x 2048 per block = 131.3 KB of the 160 KB LDS).
//   - Recurrent GEMM: gates = h @ Whh.T via v_mfma_f32_16x16x32_f16,
//     A (h) streamed from a global fp16 buffer, B (Whh rows) from LDS.
//   - dec_Wih folded to rank-4: M1 = dec_Wih@emb_W (8192x4), computed once.
//   - c/h state lives in registers of the owning thread (b = tid>>3,
//     j = bid*8 + (tid&7)); h republished as fp16 each step.
// ---------------------------------------------------------------------------

#define HID   2048
#define NBAT  64
#define TENC  128
#define TDEC  64
#define NBLK  256
#define NTHR  512
#define WROW  2056   // f16 elements per LDS weight row (4112 B, 16B aligned, +16B pad kills bank conflicts)

typedef _Float16 f16;
typedef _Float16 f16x8 __attribute__((ext_vector_type(8)));
typedef _Float16 f16x4 __attribute__((ext_vector_type(4)));
typedef float    f32x4v __attribute__((ext_vector_type(4)));

// LDS layout (bytes):
//   0      : wlds  32 x WROW f16      = 131584
//   131584 : gbuf  [64][36] f32       =   9216
//   140800 : xv    [64][4]  f32       =   1024
//   141824 : wsm   [32][4]  f32       =    512   (enc_Wih rows / M1 rows)
//   142336 : bsm   [32]     f32       =    128   (combined bias per gate row)
//   142464 : fcp   [64][4]  f32       =   1024   (fc partial sums)
//   143488 : fcw   [8][4]   f32       =    128   (fc_W slice)
#define SMEM_BYTES 143616

struct Params {
  const float* x; const int* lengths;
  const float* enc_Wih; const float* enc_Whh; const float* enc_bih; const float* enc_bhh;
  const float* emb_W; const float* emb_b;
  const float* dec_Wih; const float* dec_Whh; const float* dec_bih; const float* dec_bhh;
  const float* fc_W; const float* fc_b;
  float* dst;              // 278784 floats: preds[64][64][4], out[64][4], h[64][2048], c[64][2048]
  f16* h16;                // ws: [64][2048] fp16 published hidden state
  float* M1;               // ws: [8192][4]
  float* dbias;            // ws: [8192]
  float* obuf;             // ws: [3][64][4] triple-buffered decoder output
  unsigned* bar;           // ws: bar[0]=count, bar[16]=generation
};

__device__ __forceinline__ void gbar(unsigned* bar, unsigned& target) {
  __syncthreads();
  if (threadIdx.x == 0) {
    unsigned old = __hip_atomic_fetch_add(&bar[0], 1u, __ATOMIC_ACQ_REL, __HIP_MEMORY_SCOPE_AGENT);
    if (old == NBLK - 1) {
      __hip_atomic_store(&bar[0], 0u, __ATOMIC_RELAXED, __HIP_MEMORY_SCOPE_AGENT);
      __hip_atomic_store(&bar[16], target, __ATOMIC_RELEASE, __HIP_MEMORY_SCOPE_AGENT);
    } else {
      while (__hip_atomic_load(&bar[16], __ATOMIC_RELAXED, __HIP_MEMORY_SCOPE_AGENT) < target)
        __builtin_amdgcn_s_sleep(2);
      (void)__hip_atomic_load(&bar[16], __ATOMIC_ACQUIRE, __HIP_MEMORY_SCOPE_AGENT);
    }
  }
  __syncthreads();
  target++;
}

// Convert this block's 32 gate rows of W (fp32, row-major [8192][2048]) into LDS fp16.
__device__ __forceinline__ void fill_weights(const float* __restrict__ W, int bid,
                                             f16* wlds, int w, int l) {
  #pragma unroll
  for (int rr = 0; rr < 4; ++rr) {
    int r  = w * 4 + rr;                          // LDS row 0..31
    int gr = ((r >> 3) << 11) + bid * 8 + (r & 7); // global gate row
    const float4* src = (const float4*)(W + (size_t)gr * HID);
    f16* dst = wlds + (size_t)r * WROW;
    #pragma unroll
    for (int it = 0; it < 8; ++it) {
      float4 v = src[it * 64 + l];
      f16x4 h4; h4[0] = (f16)v.x; h4[1] = (f16)v.y; h4[2] = (f16)v.z; h4[3] = (f16)v.w;
      *(f16x4*)(dst + (it * 64 + l) * 4) = h4;
    }
  }
}

// gates += h @ Whh.T for this block's 32 gate rows. 8 waves: wave = (mh, kq),
// mh = batch half, kq = K quarter. Each wave: 2x2 accum tiles of 16x16,
// K-partials combined via LDS float atomics into gbuf[64][36].
__device__ __forceinline__ void gemm_step(const f16* __restrict__ h16, const f16* wlds,
                                          float* gbuf, int w, int l15, int quad) {
  const int mh = w & 1, kq = w >> 1;
  f32x4v a00 = {0.f,0.f,0.f,0.f}, a01 = a00, a10 = a00, a11 = a00;
  const f16* A0 = h16 + (size_t)(mh * 32 + l15) * HID + kq * 512 + quad * 8;
  const f16* A1 = A0 + (size_t)16 * HID;
  const f16* B0 = wlds + (size_t)l15 * WROW + kq * 512 + quad * 8;
  const f16* B1 = B0 + (size_t)16 * WROW;
  #pragma unroll 8
  for (int ch = 0; ch < 16; ++ch) {
    f16x8 va0 = *(const f16x8*)(A0 + ch * 32);
    f16x8 va1 = *(const f16x8*)(A1 + ch * 32);
    f16x8 vb0 = *(const f16x8*)(B0 + ch * 32);
    f16x8 vb1 = *(const f16x8*)(B1 + ch * 32);
    a00 = __builtin_amdgcn_mfma_f32_16x16x32_f16(va0, vb0, a00, 0, 0, 0);
    a01 = __builtin_amdgcn_mfma_f32_16x16x32_f16(va0, vb1, a01, 0, 0, 0);
    a10 = __builtin_amdgcn_mfma_f32_16x16x32_f16(va1, vb0, a10, 0, 0, 0);
    a11 = __builtin_amdgcn_mfma_f32_16x16x32_f16(va1, vb1, a11, 0, 0, 0);
  }
  const int brow = mh * 32 + quad * 4;
  #pragma unroll
  for (int r = 0; r < 4; ++r) {
    unsafeAtomicAdd(&gbuf[(brow + r)      * 36 +      l15], a00[r]);
    unsafeAtomicAdd(&gbuf[(brow + r)      * 36 + 16 + l15], a01[r]);
    unsafeAtomicAdd(&gbuf[(brow + 16 + r) * 36 +      l15], a10[r]);
    unsafeAtomicAdd(&gbuf[(brow + 16 + r) * 36 + 16 + l15], a11[r]);
  }
}

extern "C" __global__ void __launch_bounds__(NTHR, 1)
lstm_persistent(Params P) {
  extern __shared__ char smem[];
  f16*   wlds = (f16*)smem;
  float* gbuf = (float*)(smem + 131584);
  float* xv   = (float*)(smem + 140800);
  float* wsm  = (float*)(smem + 141824);
  float* bsm  = (float*)(smem + 142336);
  float* fcp  = (float*)(smem + 142464);
  float* fcw  = (float*)(smem + 143488);

  const int t    = threadIdx.x;
  const int bid  = blockIdx.x;
  const int w    = t >> 6;
  const int l    = t & 63;
  const int l15  = l & 15;
  const int quad = l >> 4;
  const int bb   = t >> 3;          // owned batch (0..63)
  const int jj   = t & 7;           // owned j within block slice
  const int jglob = bid * 8 + jj;   // owned hidden index (0..2047)

  unsigned target = 1;

  // ---------------- setup ----------------
  P.h16[(size_t)bid * NTHR + t] = (f16)0.f;   // zero full h16 (256*512 = 131072)

  if (t < 32) {  // cache enc_Wih rows (float4) + combined bias
    int r = t, gr = ((r >> 3) << 11) + bid * 8 + (r & 7);
    ((float4*)wsm)[r] = ((const float4*)P.enc_Wih)[gr];
    bsm[r] = P.enc_bih[gr] + P.enc_bhh[gr];
  }
  fill_weights(P.enc_Whh, bid, wlds, w, l);

  // M1 = dec_Wih @ emb_W, b1 = dec_Wih @ emb_b (this block's 32 rows; wave per row)
  #pragma unroll
  for (int rr = 0; rr < 4; ++rr) {
    int r = w * 4 + rr, gr = ((r >> 3) << 11) + bid * 8 + (r & 7);
    const float* wr = P.dec_Wih + (size_t)gr * HID;
    float a0 = 0.f, a1 = 0.f, a2 = 0.f, a3 = 0.f, ab = 0.f;
    for (int k = l; k < HID; k += 64) {
      float wv = wr[k];
      float4 e = ((const float4*)P.emb_W)[k];
      a0 += wv * e.x; a1 += wv * e.y; a2 += wv * e.z; a3 += wv * e.w;
      ab += wv * P.emb_b[k];
    }
    #pragma unroll
    for (int off = 32; off > 0; off >>= 1) {
      a0 += __shfl_xor(a0, off); a1 += __shfl_xor(a1, off);
      a2 += __shfl_xor(a2, off); a3 += __shfl_xor(a3, off);
      ab += __shfl_xor(ab, off);
    }
    if (l == 0) {
      P.M1[gr * 4 + 0] = a0; P.M1[gr * 4 + 1] = a1;
      P.M1[gr * 4 + 2] = a2; P.M1[gr * 4 + 3] = a3;
      P.dbias[gr] = ab + P.dec_bih[gr] + P.dec_bhh[gr];
    }
  }

  const int len_b = P.lengths[bb];
  float hreg = 0.f, creg = 0.f;

  gbar(P.bar, target);

  // ---------------- encoder: 128 masked steps ----------------
  for (int ts = 0; ts < TENC; ++ts) {
    if (t < NBAT) ((float4*)xv)[t] = ((const float4*)P.x)[t * TENC + ts];
    __syncthreads();
    for (int e = t; e < 2048; e += NTHR) {      // gbuf init: bias + rank-4 input
      int b = e >> 5, n = e & 31;
      float4 wv = ((const float4*)wsm)[n];
      const float* xb = xv + b * 4;
      gbuf[b * 36 + n] = bsm[n] + xb[0] * wv.x + xb[1] * wv.y + xb[2] * wv.z + xb[3] * wv.w;
    }
    __syncthreads();
    if (ts > 0) gemm_step(P.h16, wlds, gbuf, w, l15, quad);  // h==0 at ts=0
    __syncthreads();
    {
      float gi = gbuf[bb * 36 + jj],      gf = gbuf[bb * 36 + 8 + jj];
      float gg = gbuf[bb * 36 + 16 + jj], go = gbuf[bb * 36 + 24 + jj];
      float ii = 1.f / (1.f + expf(-gi));
      float ff = 1.f / (1.f + expf(-gf));
      float g  = tanhf(gg);
      float oo = 1.f / (1.f + expf(-go));
      float cn = ff * creg + ii * g;
      float hn = oo * tanhf(cn);
      if (ts < len_b) { creg = cn; hreg = hn; }   // packed-sequence freeze
      P.h16[(size_t)bb * HID + jglob] = (f16)hreg;
    }
    gbar(P.bar, target);
  }

  // ---------------- transition: decoder weights + seed ----------------
  fill_weights(P.dec_Whh, bid, wlds, w, l);
  if (t < 32) {
    int r = t, gr = ((r >> 3) << 11) + bid * 8 + (r & 7);
    ((float4*)wsm)[r] = ((const float4*)P.M1)[gr];
    bsm[r] = P.dbias[gr];
  }
  if (t < 32) {  // fcw[jj][d] = fc_W[d][bid*8+jj]
    int j2 = t >> 2, d = t & 3;
    fcw[j2 * 4 + d] = P.fc_W[d * HID + bid * 8 + j2];
  }
  if (bid == 0 && t < 256) {
    int b = t >> 2, d = t & 3;
    P.obuf[512 + t] = P.x[(b * TENC + (P.lengths[b] - 1)) * 4 + d];  // buf2 = x0 seed
    P.obuf[t]       = P.fc_b[d];                                     // buf0 init for step0 sums
  }
  gbar(P.bar, target);

  // ---------------- decoder: 64 autoregressive steps ----------------
  for (int s = 0; s < TDEC; ++s) {
    const int rbuf = (s + 2) % 3, wbuf = s % 3, zbuf = (s + 1) % 3;
    if (t < NBAT) {
      float4 o4 = ((const float4*)(P.obuf + rbuf * 256))[t];
      ((float4*)xv)[t] = o4;
      if (s >= 1) ((float4*)P.dst)[t * TDEC + (s - 1)] = o4;  // predictions[b][s-1]
    }
    if (t == 0) P.obuf[zbuf * 256 + bid] = P.fc_b[bid & 3];    // re-init future buffer
    __syncthreads();
    for (int e = t; e < 2048; e += NTHR) {   // gbuf init: dbias + rank-4(out_prev, M1)
      int b = e >> 5, n = e & 31;
      float4 wv = ((const float4*)wsm)[n];
      const float* xb = xv + b * 4;
      gbuf[b * 36 + n] = bsm[n] + xb[0] * wv.x + xb[1] * wv.y + xb[2] * wv.z + xb[3] * wv.w;
    }
    if (t < 256) fcp[t] = 0.f;
    __syncthreads();
    gemm_step(P.h16, wlds, gbuf, w, l15, quad);
    __syncthreads();
    {
      float gi = gbuf[bb * 36 + jj],      gf = gbuf[bb * 36 + 8 + jj];
      float gg = gbuf[bb * 36 + 16 + jj], go = gbuf[bb * 36 + 24 + jj];
      float ii = 1.f / (1.f + expf(-gi));
      float ff = 1.f / (1.f + expf(-gf));
      float g  = tanhf(gg);
      float oo = 1.f / (1.f + expf(-go));
      creg = ff * creg + ii * g;
      hreg = oo * tanhf(creg);
      P.h16[(size_t)bb * HID + jglob] = (f16)hreg;
      #pragma unroll
      for (int d = 0; d < 4; ++d)
        unsafeAtomicAdd(&fcp[bb * 4 + d], hreg * fcw[jj * 4 + d]);  // fc head partials
    }
    __syncthreads();
    if (t < 256) unsafeAtomicAdd(&P.obuf[wbuf * 256 + t], fcp[t]);
    gbar(P.bar, target);
  }

  // ---------------- epilogue ----------------
  if (bid == 0 && t < NBAT) {
    float4 o4 = ((const float4*)P.obuf)[t];          // step 63 wrote buf 63%3==0
    ((float4*)P.dst)[t * TDEC + 63] = o4;            // predictions[b][63]
    ((float4*)(P.dst + 16384))[t]   = o4;            // out[b][:]
  }
  P.dst[16640  + (size_t)bb * HID + jglob] = hreg;   // h
  P.dst[147712 + (size_t)bb * HID + jglob] = creg;   // c
}

extern "C" void kernel_launch(void* const* d_in, const int* in_sizes, int n_in,
                              void* d_out, int out_size, void* d_ws, size_t ws_size,
                              hipStream_t stream) {
  (void)in_sizes; (void)n_in; (void)out_size; (void)ws_size;
  Params P;
  P.x        = (const float*)d_in[0];
  P.lengths  = (const int*)  d_in[1];
  // d_in[2] = target_len (compile-time constant 64)
  P.enc_Wih  = (const float*)d_in[3];
  P.enc_Whh  = (const float*)d_in[4];
  P.enc_bih  = (const float*)d_in[5];
  P.enc_bhh  = (const float*)d_in[6];
  P.emb_W    = (const float*)d_in[7];
  P.emb_b    = (const float*)d_in[8];
  P.dec_Wih  = (const float*)d_in[9];
  P.dec_Whh  = (const float*)d_in[10];
  P.dec_bih  = (const float*)d_in[11];
  P.dec_bhh  = (const float*)d_in[12];
  P.fc_W     = (const float*)d_in[13];
  P.fc_b     = (const float*)d_in[14];
  P.dst      = (float*)d_out;

  char* ws = (char*)d_ws;
  P.h16   = (f16*)ws;                              // 262144 B
  P.M1    = (float*)(ws + 262144);                 // 131072 B
  P.dbias = (float*)(ws + 262144 + 131072);        //  32768 B
  P.obuf  = (float*)(ws + 262144 + 131072 + 32768);//   3072 B
  P.bar   = (unsigned*)(ws + 262144 + 131072 + 32768 + 4096);

  hipMemsetAsync(P.bar, 0, 256, stream);           // barrier count/gen = 0 (ws is poisoned)

  hipFuncSetAttribute((const void*)lstm_persistent,
                      hipFuncAttributeMaxDynamicSharedMemorySize, SMEM_BYTES);
  void* args[] = { &P };
  hipLaunchCooperativeKernel((const void*)lstm_persistent, dim3(NBLK), dim3(NTHR),
                             args, SMEM_BYTES, stream);
}

// Round 2
// 4934.874 us; speedup vs baseline: 1.4193x; 1.4193x over previous
//
#include <hip/hip_runtime.h>
#include <hip/hip_fp16.h>

// ---------------------------------------------------------------------------
// LSTM position predictor, persistent cooperative kernel. Round 2.
//   - Hierarchical fence-free barrier (8 group lines + 1 global + 8 gens),
//     all relaxed agent-scope atomics. No acquire/release cache storms.
//   - h16 DOUBLE-BUFFERED (fixes in-place overwrite race), stores are
//     agent-scope write-through 8B packed; reads are plain cached b128 after
//     one buffer_inv per block per step.
//   - Decoder out-reduction banked into 8 group buffers (device atomics),
//     readers sum 8 groups + fc_b. Single rotating prediction writer.
//   - Whh fp16 persistent in LDS (131.3 KB); dec_Wih folded rank-4 via
//     emb_W (M1 computed straight into LDS at the transition).
// ---------------------------------------------------------------------------

#define HID   2048
#define NBAT  64
#define TENC  128
#define TDEC  64
#define NBLK  256
#define NTHR  512
#define WROW  2056   // f16 per LDS weight row (+8 pad, 16B aligned)

typedef _Float16 f16;
typedef _Float16 f16x8 __attribute__((ext_vector_type(8)));
typedef _Float16 f16x4 __attribute__((ext_vector_type(4)));
typedef float    f32x4v __attribute__((ext_vector_type(4)));

// LDS layout (bytes):
//   0      : wlds  32 x WROW f16      = 131584
//   131584 : gbuf  [64][36] f32       =   9216
//   140800 : xv    [64][4]  f32       =   1024
//   141824 : wsm   [32][4]  f32       =    512
//   142336 : bsm   [32]     f32       =    128
//   142464 : fcp  [64][4]   f32       =   1024
//   143488 : fcw  [8][4]    f32       =    128
#define SMEM_BYTES 143616

struct Params {
  const float* x; const int* lengths;
  const float* enc_Wih; const float* enc_Whh; const float* enc_bih; const float* enc_bhh;
  const float* emb_W; const float* emb_b;
  const float* dec_Wih; const float* dec_Whh; const float* dec_bih; const float* dec_bhh;
  const float* fc_W; const float* fc_b;
  float* dst;        // 278784 floats: preds[64][64][4], out[64][4], h[64][2048], c[64][2048]
  f16* h16;          // ws: [2][64][2048] double-buffered hidden state
  float* obg;        // ws: [8][3][256] banked decoder-out partials
  unsigned* bar;     // ws: gc[8]@g*64, global@512, gens[8]@576+g*64
};

__device__ __forceinline__ void astore_f32(float* p, float v) {
  __hip_atomic_store(p, v, __ATOMIC_RELAXED, __HIP_MEMORY_SCOPE_AGENT);
}
__device__ __forceinline__ void astore_u64(float* p, unsigned long long v) {
  __hip_atomic_store((unsigned long long*)p, v, __ATOMIC_RELAXED, __HIP_MEMORY_SCOPE_AGENT);
}
__device__ __forceinline__ float2 aload_f32x2(const float* p) {
  unsigned long long q = __hip_atomic_load((const unsigned long long*)p,
                                           __ATOMIC_RELAXED, __HIP_MEMORY_SCOPE_AGENT);
  union { unsigned long long u; float2 f; } x; x.u = q; return x.f;
}
// Invalidate L1 + (XCD) L2 so plain loads refetch cross-XCD data from the
// coherence point. All shared writes in the loop bypass caches (agent-scope /
// device atomics), so no dirty-line hazard exists.
__device__ __forceinline__ void cache_inv() {
  asm volatile("buffer_inv sc0 sc1\n\ts_waitcnt vmcnt(0)" ::: "memory");
}

// Hierarchical fence-free grid barrier. Monotonic counters, no resets.
// h16/obg visibility: their stores are write-through to the coherence point
// and vmcnt-drained by __syncthreads before thread 0 arrives.
__device__ __forceinline__ void gbar(unsigned* bar, unsigned& target) {
  __syncthreads();
  if (threadIdx.x == 0) {
    const int g = blockIdx.x & 7;
    unsigned old = __hip_atomic_fetch_add(&bar[g * 64], 1u,
                                          __ATOMIC_RELAXED, __HIP_MEMORY_SCOPE_AGENT);
    if (old == target * 32u - 1u) {                    // last in group
      unsigned go = __hip_atomic_fetch_add(&bar[512], 1u,
                                           __ATOMIC_RELAXED, __HIP_MEMORY_SCOPE_AGENT);
      if (go == target * 8u - 1u) {                    // last group
        #pragma unroll
        for (int i = 0; i < 8; ++i)
          __hip_atomic_store(&bar[576 + i * 64], target,
                             __ATOMIC_RELAXED, __HIP_MEMORY_SCOPE_AGENT);
      }
    }
    while (__hip_atomic_load(&bar[576 + g * 64],
                             __ATOMIC_RELAXED, __HIP_MEMORY_SCOPE_AGENT) < target)
      __builtin_amdgcn_s_sleep(2);
  }
  __syncthreads();
  target++;
}

// Convert this block's 32 gate rows of W (fp32 [8192][2048]) into LDS fp16.
__device__ __forceinline__ void fill_weights(const float* __restrict__ W, int bid,
                                             f16* wlds, int w, int l) {
  #pragma unroll
  for (int rr = 0; rr < 4; ++rr) {
    int r  = w * 4 + rr;
    int gr = ((r >> 3) << 11) + bid * 8 + (r & 7);
    const float4* src = (const float4*)(W + (size_t)gr * HID);
    f16* dst = wlds + (size_t)r * WROW;
    #pragma unroll
    for (int it = 0; it < 8; ++it) {
      float4 v = src[it * 64 + l];
      f16x4 h4; h4[0] = (f16)v.x; h4[1] = (f16)v.y; h4[2] = (f16)v.z; h4[3] = (f16)v.w;
      *(f16x4*)(dst + (it * 64 + l) * 4) = h4;
    }
  }
}

// gates += h @ Whh.T for this block's 32 gate rows (plain cached loads of h16p).
__device__ __forceinline__ void gemm_step(const f16* __restrict__ h16p, const f16* wlds,
                                          float* gbuf, int w, int l15, int quad) {
  const int mh = w & 1, kq = w >> 1;
  f32x4v a00 = {0.f,0.f,0.f,0.f}, a01 = a00, a10 = a00, a11 = a00;
  const f16* A0 = h16p + (size_t)(mh * 32 + l15) * HID + kq * 512 + quad * 8;
  const f16* A1 = A0 + (size_t)16 * HID;
  const f16* B0 = wlds + (size_t)l15 * WROW + kq * 512 + quad * 8;
  const f16* B1 = B0 + (size_t)16 * WROW;
  #pragma unroll 8
  for (int ch = 0; ch < 16; ++ch) {
    f16x8 va0 = *(const f16x8*)(A0 + ch * 32);
    f16x8 va1 = *(const f16x8*)(A1 + ch * 32);
    f16x8 vb0 = *(const f16x8*)(B0 + ch * 32);
    f16x8 vb1 = *(const f16x8*)(B1 + ch * 32);
    a00 = __builtin_amdgcn_mfma_f32_16x16x32_f16(va0, vb0, a00, 0, 0, 0);
    a01 = __builtin_amdgcn_mfma_f32_16x16x32_f16(va0, vb1, a01, 0, 0, 0);
    a10 = __builtin_amdgcn_mfma_f32_16x16x32_f16(va1, vb0, a10, 0, 0, 0);
    a11 = __builtin_amdgcn_mfma_f32_16x16x32_f16(va1, vb1, a11, 0, 0, 0);
  }
  const int brow = mh * 32 + quad * 4;
  #pragma unroll
  for (int r = 0; r < 4; ++r) {
    unsafeAtomicAdd(&gbuf[(brow + r)      * 36 +      l15], a00[r]);
    unsafeAtomicAdd(&gbuf[(brow + r)      * 36 + 16 + l15], a01[r]);
    unsafeAtomicAdd(&gbuf[(brow + 16 + r) * 36 +      l15], a10[r]);
    unsafeAtomicAdd(&gbuf[(brow + 16 + r) * 36 + 16 + l15], a11[r]);
  }
}

extern "C" __global__ void __launch_bounds__(NTHR, 1)
lstm_persistent(Params P) {
  extern __shared__ char smem[];
  f16*   wlds = (f16*)smem;
  float* gbuf = (float*)(smem + 131584);
  float* xv   = (float*)(smem + 140800);
  float* wsm  = (float*)(smem + 141824);
  float* bsm  = (float*)(smem + 142336);
  float* fcp  = (float*)(smem + 142464);
  float* fcw  = (float*)(smem + 143488);

  const int t    = threadIdx.x;
  const int bid  = blockIdx.x;
  const int w    = t >> 6;
  const int l    = t & 63;
  const int l15  = l & 15;
  const int quad = l >> 4;
  const int bb   = t >> 3;
  const int jj   = t & 7;
  const int jglob = bid * 8 + jj;

  unsigned target = 1;

  // ---------------- setup (all block-local; no barrier needed) ----------------
  if (t < 32) {
    int r = t, gr = ((r >> 3) << 11) + bid * 8 + (r & 7);
    ((float4*)wsm)[r] = ((const float4*)P.enc_Wih)[gr];
    bsm[r] = P.enc_bih[gr] + P.enc_bhh[gr];
  }
  fill_weights(P.enc_Whh, bid, wlds, w, l);

  const int len_b = P.lengths[bb];
  const float4 fcb = ((const float4*)P.fc_b)[0];
  float hreg = 0.f, creg = 0.f;

  // ---------------- encoder: 128 masked steps ----------------
  for (int ts = 0; ts < TENC; ++ts) {
    const int rp = ts & 1, wp = (ts + 1) & 1;
    if (w == 0) {
      cache_inv();
      if (t < NBAT) ((float4*)xv)[t] = ((const float4*)P.x)[t * TENC + ts];
    }
    __syncthreads();
    for (int e = t; e < 2048; e += NTHR) {      // gbuf = bias + rank-4 input
      int b = e >> 5, n = e & 31;
      float4 wv = ((const float4*)wsm)[n];
      const float* xb = xv + b * 4;
      gbuf[b * 36 + n] = bsm[n] + xb[0] * wv.x + xb[1] * wv.y + xb[2] * wv.z + xb[3] * wv.w;
    }
    __syncthreads();
    if (ts > 0) gemm_step(P.h16 + (size_t)rp * NBAT * HID, wlds, gbuf, w, l15, quad);
    __syncthreads();
    {
      float gi = gbuf[bb * 36 + jj],      gf = gbuf[bb * 36 + 8 + jj];
      float gg = gbuf[bb * 36 + 16 + jj], go = gbuf[bb * 36 + 24 + jj];
      float ii = 1.f / (1.f + expf(-gi));
      float ff = 1.f / (1.f + expf(-gf));
      float g  = tanhf(gg);
      float oo = 1.f / (1.f + expf(-go));
      float cn = ff * creg + ii * g;
      float hn = oo * tanhf(cn);
      if (ts < len_b) { creg = cn; hreg = hn; }   // packed-sequence freeze
      unsigned hv = (unsigned)__builtin_bit_cast(unsigned short, (f16)hreg);
      unsigned v1 = __shfl_down(hv, 1), v2 = __shfl_down(hv, 2), v3 = __shfl_down(hv, 3);
      if ((t & 3) == 0) {
        unsigned long long pk = (unsigned long long)hv | ((unsigned long long)v1 << 16)
                              | ((unsigned long long)v2 << 32) | ((unsigned long long)v3 << 48);
        astore_u64((float*)(P.h16 + (size_t)wp * NBAT * HID + (size_t)bb * HID + bid * 8 + (jj & 4)), pk);
      }
    }
    gbar(P.bar, target);
  }

  // ---------------- transition: decoder weights + folded M1 + seed ----------------
  fill_weights(P.dec_Whh, bid, wlds, w, l);
  #pragma unroll
  for (int rr = 0; rr < 4; ++rr) {       // M1 = dec_Wih@emb_W straight into LDS
    int r = w * 4 + rr, gr = ((r >> 3) << 11) + bid * 8 + (r & 7);
    const float* wr = P.dec_Wih + (size_t)gr * HID;
    float a0 = 0.f, a1 = 0.f, a2 = 0.f, a3 = 0.f, ab = 0.f;
    for (int k = l; k < HID; k += 64) {
      float wv = wr[k];
      float4 e = ((const float4*)P.emb_W)[k];
      a0 += wv * e.x; a1 += wv * e.y; a2 += wv * e.z; a3 += wv * e.w;
      ab += wv * P.emb_b[k];
    }
    #pragma unroll
    for (int off = 32; off > 0; off >>= 1) {
      a0 += __shfl_xor(a0, off); a1 += __shfl_xor(a1, off);
      a2 += __shfl_xor(a2, off); a3 += __shfl_xor(a3, off);
      ab += __shfl_xor(ab, off);
    }
    if (l == 0) {
      wsm[r * 4 + 0] = a0; wsm[r * 4 + 1] = a1; wsm[r * 4 + 2] = a2; wsm[r * 4 + 3] = a3;
      bsm[r] = ab + P.dec_bih[gr] + P.dec_bhh[gr];
    }
  }
  if (t < 32) {  // fcw[j][d]
    int j2 = t >> 2, d = t & 3;
    fcw[j2 * 4 + d] = P.fc_W[d * HID + bid * 8 + j2];
  }
  if (bid < 8 && t < 256) {   // seed buf2 (group0 = x0 - fc_b, rest 0); zero buf0
    int b = t >> 2, d = t & 3;
    float v = 0.f;
    if (bid == 0) v = P.x[((size_t)b * TENC + (P.lengths[b] - 1)) * 4 + d] - P.fc_b[d];
    astore_f32(&P.obg[(bid * 3 + 2) * 256 + t], v);
    astore_f32(&P.obg[(bid * 3 + 0) * 256 + t], 0.f);
  }
  gbar(P.bar, target);

  // ---------------- decoder: 64 autoregressive steps ----------------
  for (int s = 0; s < TDEC; ++s) {
    const int rp = s & 1, wp = (s + 1) & 1;
    const int rbuf = (s + 2) % 3, wbuf = s % 3, zbuf = (s + 1) % 3;
    if (w == 0) {
      cache_inv();
      if (t < NBAT) {
        float4 acc = fcb;                       // out(s-1) = fc_b + sum of 8 group partials
        #pragma unroll
        for (int g = 0; g < 8; ++g) {
          const float* pp = P.obg + (g * 3 + rbuf) * 256 + t * 4;
          float2 lo = aload_f32x2(pp), hi = aload_f32x2(pp + 2);
          acc.x += lo.x; acc.y += lo.y; acc.z += hi.x; acc.w += hi.y;
        }
        ((float4*)xv)[t] = acc;
        if (s >= 1 && bid == s) {               // rotating prediction writer
          union { float2 f; unsigned long long u; } q0, q1;
          q0.f.x = acc.x; q0.f.y = acc.y; q1.f.x = acc.z; q1.f.y = acc.w;
          float* dp = P.dst + ((size_t)t * TDEC + (s - 1)) * 4;
          astore_u64(dp, q0.u); astore_u64(dp + 2, q1.u);
        }
      }
    }
    if (bid < 8 && t < 256) astore_f32(&P.obg[(bid * 3 + zbuf) * 256 + t], 0.f);
    if (t < 256) fcp[t] = 0.f;
    __syncthreads();
    for (int e = t; e < 2048; e += NTHR) {      // gbuf = dbias + rank-4(out_prev, M1)
      int b = e >> 5, n = e & 31;
      float4 wv = ((const float4*)wsm)[n];
      const float* xb = xv + b * 4;
      gbuf[b * 36 + n] = bsm[n] + xb[0] * wv.x + xb[1] * wv.y + xb[2] * wv.z + xb[3] * wv.w;
    }
    __syncthreads();
    gemm_step(P.h16 + (size_t)rp * NBAT * HID, wlds, gbuf, w, l15, quad);
    __syncthreads();
    {
      float gi = gbuf[bb * 36 + jj],      gf = gbuf[bb * 36 + 8 + jj];
      float gg = gbuf[bb * 36 + 16 + jj], go = gbuf[bb * 36 + 24 + jj];
      float ii = 1.f / (1.f + expf(-gi));
      float ff = 1.f / (1.f + expf(-gf));
      float g  = tanhf(gg);
      float oo = 1.f / (1.f + expf(-go));
      creg = ff * creg + ii * g;
      hreg = oo * tanhf(creg);
      unsigned hv = (unsigned)__builtin_bit_cast(unsigned short, (f16)hreg);
      unsigned v1 = __shfl_down(hv, 1), v2 = __shfl_down(hv, 2), v3 = __shfl_down(hv, 3);
      if ((t & 3) == 0) {
        unsigned long long pk = (unsigned long long)hv | ((unsigned long long)v1 << 16)
                              | ((unsigned long long)v2 << 32) | ((unsigned long long)v3 << 48);
        astore_u64((float*)(P.h16 + (size_t)wp * NBAT * HID + (size_t)bb * HID + bid * 8 + (jj & 4)), pk);
      }
      #pragma unroll
      for (int d = 0; d < 4; ++d)
        unsafeAtomicAdd(&fcp[bb * 4 + d], hreg * fcw[jj * 4 + d]);
    }
    __syncthreads();
    if (t < 256) unsafeAtomicAdd(&P.obg[((bid & 7) * 3 + wbuf) * 256 + t], fcp[t]);
    gbar(P.bar, target);
  }

  // ---------------- epilogue (after final barrier; no more invs anywhere) ----------------
  if (bid == 0 && t < NBAT) {
    float4 acc = fcb;                            // out(63): wbuf at s=63 is 0
    #pragma unroll
    for (int g = 0; g < 8; ++g) {
      const float* pp = P.obg + (g * 3 + 0) * 256 + t * 4;
      float2 lo = aload_f32x2(pp), hi = aload_f32x2(pp + 2);
      acc.x += lo.x; acc.y += lo.y; acc.z += hi.x; acc.w += hi.y;
    }
    ((float4*)P.dst)[t * TDEC + 63] = acc;       // predictions[b][63]
    ((float4*)(P.dst + 16384))[t]   = acc;       // out
  }
  P.dst[16640  + (size_t)bb * HID + jglob] = hreg;   // h
  P.dst[147712 + (size_t)bb * HID + jglob] = creg;   // c
}

extern "C" void kernel_launch(void* const* d_in, const int* in_sizes, int n_in,
                              void* d_out, int out_size, void* d_ws, size_t ws_size,
                              hipStream_t stream) {
  (void)in_sizes; (void)n_in; (void)out_size; (void)ws_size;
  Params P;
  P.x        = (const float*)d_in[0];
  P.lengths  = (const int*)  d_in[1];
  // d_in[2] = target_len (constant 64)
  P.enc_Wih  = (const float*)d_in[3];
  P.enc_Whh  = (const float*)d_in[4];
  P.enc_bih  = (const float*)d_in[5];
  P.enc_bhh  = (const float*)d_in[6];
  P.emb_W    = (const float*)d_in[7];
  P.emb_b    = (const float*)d_in[8];
  P.dec_Wih  = (const float*)d_in[9];
  P.dec_Whh  = (const float*)d_in[10];
  P.dec_bih  = (const float*)d_in[11];
  P.dec_bhh  = (const float*)d_in[12];
  P.fc_W     = (const float*)d_in[13];
  P.fc_b     = (const float*)d_in[14];
  P.dst      = (float*)d_out;

  char* ws = (char*)d_ws;
  P.h16 = (f16*)ws;                                  // 2*64*2048*2 = 524288 B
  P.obg = (float*)(ws + 524288);                     // 8*3*256*4   =  24576 B
  P.bar = (unsigned*)(ws + 524288 + 24576);          //               8192 B

  hipMemsetAsync(P.bar, 0, 8192, stream);            // ws is poisoned 0xAA

  hipFuncSetAttribute((const void*)lstm_persistent,
                      hipFuncAttributeMaxDynamicSharedMemorySize, SMEM_BYTES);
  void* args[] = { &P };
  hipLaunchCooperativeKernel((const void*)lstm_persistent, dim3(NBLK), dim3(NTHR),
                             args, SMEM_BYTES, stream);
}

// Round 3
// 4684.634 us; speedup vs baseline: 1.4952x; 1.0534x over previous
//
#include <hip/hip_runtime.h>
#include <hip/hip_fp16.h>

// ---------------------------------------------------------------------------
// LSTM position predictor, persistent cooperative kernel. Round 3.
//   KEY CHANGE vs round 2: the per-block `buffer_inv sc0 sc1` per step (the
//   inv storm: 32 invs/XCD/step serializing at each L2 and re-clobbering
//   freshly fetched h16 lines) is replaced by ONE L2 inv per XCD per step:
//     - per-XCD leader (rank 0 via HW_REG_XCC_ID) polls the global release,
//       issues buffer_inv sc0 sc1, publishes per-XCD generation;
//     - other 31 blocks poll their XCD gen (agent loads) and do an L1-only
//       buffer_inv sc0 (per-CU, cheap).
//   GEMM h16 reads stay plain cached loads -> L2 multicast per XCD.
//   Everything else (fp16 weights persistent in LDS, rank-4 folded dec_Wih,
//   double-buffered h16, banked decoder reduction) unchanged from round 2.
// ---------------------------------------------------------------------------

#define HID   2048
#define NBAT  64
#define TENC  128
#define TDEC  64
#define NBLK  256
#define NTHR  512
#define WROW  2056   // f16 per LDS weight row (+8 pad, 16B aligned)

typedef _Float16 f16;
typedef _Float16 f16x8 __attribute__((ext_vector_type(8)));
typedef _Float16 f16x4 __attribute__((ext_vector_type(4)));
typedef float    f32x4v __attribute__((ext_vector_type(4)));

// LDS layout (bytes):
//   0      : wlds  32 x WROW f16      = 131584
//   131584 : gbuf  [64][36] f32       =   9216
//   140800 : xv    [64][4]  f32       =   1024
//   141824 : wsm   [32][4]  f32       =    512
//   142336 : bsm   [32]     f32       =    128
//   142464 : fcp  [64][4]   f32       =   1024
//   143488 : fcw  [8][4]    f32       =    128
#define SMEM_BYTES 143616

struct Params {
  const float* x; const int* lengths;
  const float* enc_Wih; const float* enc_Whh; const float* enc_bih; const float* enc_bhh;
  const float* emb_W; const float* emb_b;
  const float* dec_Wih; const float* dec_Whh; const float* dec_bih; const float* dec_bhh;
  const float* fc_W; const float* fc_b;
  float* dst;        // 278784 floats: preds[64][64][4], out[64][4], h[64][2048], c[64][2048]
  f16* h16;          // ws: [2][64][2048] double-buffered hidden state
  float* obg;        // ws: [8][3][256] banked decoder-out partials
  unsigned* bar;     // ws: arrival g*64 (g<8), global@512, gen@576,
                     //     xcdgen@640+x*64 (x<16), xcdrank@1664+x*64 (x<16)
};

__device__ __forceinline__ void astore_f32(float* p, float v) {
  __hip_atomic_store(p, v, __ATOMIC_RELAXED, __HIP_MEMORY_SCOPE_AGENT);
}
__device__ __forceinline__ void astore_u64(float* p, unsigned long long v) {
  __hip_atomic_store((unsigned long long*)p, v, __ATOMIC_RELAXED, __HIP_MEMORY_SCOPE_AGENT);
}
__device__ __forceinline__ float2 aload_f32x2(const float* p) {
  unsigned long long q = __hip_atomic_load((const unsigned long long*)p,
                                           __ATOMIC_RELAXED, __HIP_MEMORY_SCOPE_AGENT);
  union { unsigned long long u; float2 f; } x; x.u = q; return x.f;
}

__device__ __forceinline__ unsigned xcc_id() {
  unsigned x;
  asm("s_getreg_b32 %0, hwreg(20, 0, 32)" : "=s"(x));   // HW_REG_XCC_ID
  return x & 15u;
}

// 3-stage grid barrier with per-XCD single L2 invalidate.
// Stage 1: hierarchical relaxed arrival (8 lines x 32 + 1 global).
// Stage 2: global gen released by last arriver.
// Stage 3: per-XCD leader sees gen, invs L2 (+own L1), publishes xcdgen;
//          waiters see xcdgen (agent loads bypass caches), inv their L1 only.
__device__ __forceinline__ void gbar(unsigned* bar, unsigned& target,
                                     unsigned xcc, bool leader) {
  __syncthreads();   // drains this block's vmem stores before arrival
  if (threadIdx.x == 0) {
    const int g = blockIdx.x & 7;
    unsigned old = __hip_atomic_fetch_add(&bar[g * 64], 1u,
                                          __ATOMIC_RELAXED, __HIP_MEMORY_SCOPE_AGENT);
    if (old == target * 32u - 1u) {                    // last in arrival group
      unsigned go = __hip_atomic_fetch_add(&bar[512], 1u,
                                           __ATOMIC_RELAXED, __HIP_MEMORY_SCOPE_AGENT);
      if (go == target * 8u - 1u)                      // last group -> release
        __hip_atomic_store(&bar[576], target,
                           __ATOMIC_RELAXED, __HIP_MEMORY_SCOPE_AGENT);
    }
    if (leader) {
      while (__hip_atomic_load(&bar[576], __ATOMIC_RELAXED,
                               __HIP_MEMORY_SCOPE_AGENT) < target)
        __builtin_amdgcn_s_sleep(1);
      asm volatile("s_waitcnt vmcnt(0)\n\t"
                   "buffer_inv sc0 sc1\n\t"
                   "s_waitcnt vmcnt(0)" ::: "memory");  // one L2 inv per XCD
      __hip_atomic_store(&bar[640 + xcc * 64], target,
                         __ATOMIC_RELAXED, __HIP_MEMORY_SCOPE_AGENT);
    } else {
      while (__hip_atomic_load(&bar[640 + xcc * 64], __ATOMIC_RELAXED,
                               __HIP_MEMORY_SCOPE_AGENT) < target)
        __builtin_amdgcn_s_sleep(1);
      asm volatile("buffer_inv sc0\n\t"
                   "s_waitcnt vmcnt(0)" ::: "memory");  // own L1 only
    }
  }
  __syncthreads();
  target++;
}

// Convert this block's 32 gate rows of W (fp32 [8192][2048]) into LDS fp16.
__device__ __forceinline__ void fill_weights(const float* __restrict__ W, int bid,
                                             f16* wlds, int w, int l) {
  #pragma unroll
  for (int rr = 0; rr < 4; ++rr) {
    int r  = w * 4 + rr;
    int gr = ((r >> 3) << 11) + bid * 8 + (r & 7);
    const float4* src = (const float4*)(W + (size_t)gr * HID);
    f16* dst = wlds + (size_t)r * WROW;
    #pragma unroll
    for (int it = 0; it < 8; ++it) {
      float4 v = src[it * 64 + l];
      f16x4 h4; h4[0] = (f16)v.x; h4[1] = (f16)v.y; h4[2] = (f16)v.z; h4[3] = (f16)v.w;
      *(f16x4*)(dst + (it * 64 + l) * 4) = h4;
    }
  }
}

// gates += h @ Whh.T for this block's 32 gate rows (plain cached loads of h16p).
__device__ __forceinline__ void gemm_step(const f16* __restrict__ h16p, const f16* wlds,
                                          float* gbuf, int w, int l15, int quad) {
  const int mh = w & 1, kq = w >> 1;
  f32x4v a00 = {0.f,0.f,0.f,0.f}, a01 = a00, a10 = a00, a11 = a00;
  const f16* A0 = h16p + (size_t)(mh * 32 + l15) * HID + kq * 512 + quad * 8;
  const f16* A1 = A0 + (size_t)16 * HID;
  const f16* B0 = wlds + (size_t)l15 * WROW + kq * 512 + quad * 8;
  const f16* B1 = B0 + (size_t)16 * WROW;
  #pragma unroll 8
  for (int ch = 0; ch < 16; ++ch) {
    f16x8 va0 = *(const f16x8*)(A0 + ch * 32);
    f16x8 va1 = *(const f16x8*)(A1 + ch * 32);
    f16x8 vb0 = *(const f16x8*)(B0 + ch * 32);
    f16x8 vb1 = *(const f16x8*)(B1 + ch * 32);
    a00 = __builtin_amdgcn_mfma_f32_16x16x32_f16(va0, vb0, a00, 0, 0, 0);
    a01 = __builtin_amdgcn_mfma_f32_16x16x32_f16(va0, vb1, a01, 0, 0, 0);
    a10 = __builtin_amdgcn_mfma_f32_16x16x32_f16(va1, vb0, a10, 0, 0, 0);
    a11 = __builtin_amdgcn_mfma_f32_16x16x32_f16(va1, vb1, a11, 0, 0, 0);
  }
  const int brow = mh * 32 + quad * 4;
  #pragma unroll
  for (int r = 0; r < 4; ++r) {
    unsafeAtomicAdd(&gbuf[(brow + r)      * 36 +      l15], a00[r]);
    unsafeAtomicAdd(&gbuf[(brow + r)      * 36 + 16 + l15], a01[r]);
    unsafeAtomicAdd(&gbuf[(brow + 16 + r) * 36 +      l15], a10[r]);
    unsafeAtomicAdd(&gbuf[(brow + 16 + r) * 36 + 16 + l15], a11[r]);
  }
}

extern "C" __global__ void __launch_bounds__(NTHR, 1)
lstm_persistent(Params P) {
  extern __shared__ char smem[];
  f16*   wlds = (f16*)smem;
  float* gbuf = (float*)(smem + 131584);
  float* xv   = (float*)(smem + 140800);
  float* wsm  = (float*)(smem + 141824);
  float* bsm  = (float*)(smem + 142336);
  float* fcp  = (float*)(smem + 142464);
  float* fcw  = (float*)(smem + 143488);

  const int t    = threadIdx.x;
  const int bid  = blockIdx.x;
  const int w    = t >> 6;
  const int l    = t & 63;
  const int l15  = l & 15;
  const int quad = l >> 4;
  const int bb   = t >> 3;
  const int jj   = t & 7;
  const int jglob = bid * 8 + jj;

  unsigned target = 1;

  // ---------------- setup (block-local) ----------------
  const unsigned xcc = xcc_id();
  bool leader = false;
  if (t == 0) {
    unsigned r = __hip_atomic_fetch_add(&P.bar[1664 + xcc * 64], 1u,
                                        __ATOMIC_RELAXED, __HIP_MEMORY_SCOPE_AGENT);
    leader = (r == 0u);
  }

  if (t < 32) {
    int r = t, gr = ((r >> 3) << 11) + bid * 8 + (r & 7);
    ((float4*)wsm)[r] = ((const float4*)P.enc_Wih)[gr];
    bsm[r] = P.enc_bih[gr] + P.enc_bhh[gr];
  }
  fill_weights(P.enc_Whh, bid, wlds, w, l);

  const int len_b = P.lengths[bb];
  const float4 fcb = ((const float4*)P.fc_b)[0];
  float hreg = 0.f, creg = 0.f;

  // ---------------- encoder: 128 masked steps ----------------
  for (int ts = 0; ts < TENC; ++ts) {
    const int rp = ts & 1, wp = (ts + 1) & 1;
    if (t < NBAT) ((float4*)xv)[t] = ((const float4*)P.x)[t * TENC + ts];
    __syncthreads();
    for (int e = t; e < 2048; e += NTHR) {      // gbuf = bias + rank-4 input
      int b = e >> 5, n = e & 31;
      float4 wv = ((const float4*)wsm)[n];
      const float* xb = xv + b * 4;
      gbuf[b * 36 + n] = bsm[n] + xb[0] * wv.x + xb[1] * wv.y + xb[2] * wv.z + xb[3] * wv.w;
    }
    __syncthreads();
    if (ts > 0) gemm_step(P.h16 + (size_t)rp * NBAT * HID, wlds, gbuf, w, l15, quad);
    __syncthreads();
    {
      float gi = gbuf[bb * 36 + jj],      gf = gbuf[bb * 36 + 8 + jj];
      float gg = gbuf[bb * 36 + 16 + jj], go = gbuf[bb * 36 + 24 + jj];
      float ii = 1.f / (1.f + expf(-gi));
      float ff = 1.f / (1.f + expf(-gf));
      float g  = tanhf(gg);
      float oo = 1.f / (1.f + expf(-go));
      float cn = ff * creg + ii * g;
      float hn = oo * tanhf(cn);
      if (ts < len_b) { creg = cn; hreg = hn; }   // packed-sequence freeze
      unsigned hv = (unsigned)__builtin_bit_cast(unsigned short, (f16)hreg);
      unsigned v1 = __shfl_down(hv, 1), v2 = __shfl_down(hv, 2), v3 = __shfl_down(hv, 3);
      if ((t & 3) == 0) {
        unsigned long long pk = (unsigned long long)hv | ((unsigned long long)v1 << 16)
                              | ((unsigned long long)v2 << 32) | ((unsigned long long)v3 << 48);
        astore_u64((float*)(P.h16 + (size_t)wp * NBAT * HID + (size_t)bb * HID + bid * 8 + (jj & 4)), pk);
      }
    }
    gbar(P.bar, target, xcc, leader);
  }

  // ---------------- transition: decoder weights + folded M1 + seed ----------------
  fill_weights(P.dec_Whh, bid, wlds, w, l);
  #pragma unroll
  for (int rr = 0; rr < 4; ++rr) {       // M1 = dec_Wih@emb_W straight into LDS
    int r = w * 4 + rr, gr = ((r >> 3) << 11) + bid * 8 + (r & 7);
    const float* wr = P.dec_Wih + (size_t)gr * HID;
    float a0 = 0.f, a1 = 0.f, a2 = 0.f, a3 = 0.f, ab = 0.f;
    for (int k = l; k < HID; k += 64) {
      float wv = wr[k];
      float4 e = ((const float4*)P.emb_W)[k];
      a0 += wv * e.x; a1 += wv * e.y; a2 += wv * e.z; a3 += wv * e.w;
      ab += wv * P.emb_b[k];
    }
    #pragma unroll
    for (int off = 32; off > 0; off >>= 1) {
      a0 += __shfl_xor(a0, off); a1 += __shfl_xor(a1, off);
      a2 += __shfl_xor(a2, off); a3 += __shfl_xor(a3, off);
      ab += __shfl_xor(ab, off);
    }
    if (l == 0) {
      wsm[r * 4 + 0] = a0; wsm[r * 4 + 1] = a1; wsm[r * 4 + 2] = a2; wsm[r * 4 + 3] = a3;
      bsm[r] = ab + P.dec_bih[gr] + P.dec_bhh[gr];
    }
  }
  if (t < 32) {  // fcw[j][d]
    int j2 = t >> 2, d = t & 3;
    fcw[j2 * 4 + d] = P.fc_W[d * HID + bid * 8 + j2];
  }
  if (bid < 8 && t < 256) {   // seed buf2 (group0 = x0 - fc_b, rest 0); zero buf0
    int b = t >> 2, d = t & 3;
    float v = 0.f;
    if (bid == 0) v = P.x[((size_t)b * TENC + (P.lengths[b] - 1)) * 4 + d] - P.fc_b[d];
    astore_f32(&P.obg[(bid * 3 + 2) * 256 + t], v);
    astore_f32(&P.obg[(bid * 3 + 0) * 256 + t], 0.f);
  }
  gbar(P.bar, target, xcc, leader);

  // ---------------- decoder: 64 autoregressive steps ----------------
  for (int s = 0; s < TDEC; ++s) {
    const int rp = s & 1, wp = (s + 1) & 1;
    const int rbuf = (s + 2) % 3, wbuf = s % 3, zbuf = (s + 1) % 3;
    if (w == 0 && t < NBAT) {
      float4 acc = fcb;                       // out(s-1) = fc_b + sum of 8 group partials
      #pragma unroll
      for (int g = 0; g < 8; ++g) {
        const float* pp = P.obg + (g * 3 + rbuf) * 256 + t * 4;
        float2 lo = aload_f32x2(pp), hi = aload_f32x2(pp + 2);
        acc.x += lo.x; acc.y += lo.y; acc.z += hi.x; acc.w += hi.y;
      }
      ((float4*)xv)[t] = acc;
      if (s >= 1 && bid == s) {               // rotating prediction writer
        union { float2 f; unsigned long long u; } q0, q1;
        q0.f.x = acc.x; q0.f.y = acc.y; q1.f.x = acc.z; q1.f.y = acc.w;
        float* dp = P.dst + ((size_t)t * TDEC + (s - 1)) * 4;
        astore_u64(dp, q0.u); astore_u64(dp + 2, q1.u);
      }
    }
    if (bid < 8 && t < 256) astore_f32(&P.obg[(bid * 3 + zbuf) * 256 + t], 0.f);
    if (t < 256) fcp[t] = 0.f;
    __syncthreads();
    for (int e = t; e < 2048; e += NTHR) {      // gbuf = dbias + rank-4(out_prev, M1)
      int b = e >> 5, n = e & 31;
      float4 wv = ((const float4*)wsm)[n];
      const float* xb = xv + b * 4;
      gbuf[b * 36 + n] = bsm[n] + xb[0] * wv.x + xb[1] * wv.y + xb[2] * wv.z + xb[3] * wv.w;
    }
    __syncthreads();
    gemm_step(P.h16 + (size_t)rp * NBAT * HID, wlds, gbuf, w, l15, quad);
    __syncthreads();
    {
      float gi = gbuf[bb * 36 + jj],      gf = gbuf[bb * 36 + 8 + jj];
      float gg = gbuf[bb * 36 + 16 + jj], go = gbuf[bb * 36 + 24 + jj];
      float ii = 1.f / (1.f + expf(-gi));
      float ff = 1.f / (1.f + expf(-gf));
      float g  = tanhf(gg);
      float oo = 1.f / (1.f + expf(-go));
      creg = ff * creg + ii * g;
      hreg = oo * tanhf(creg);
      unsigned hv = (unsigned)__builtin_bit_cast(unsigned short, (f16)hreg);
      unsigned v1 = __shfl_down(hv, 1), v2 = __shfl_down(hv, 2), v3 = __shfl_down(hv, 3);
      if ((t & 3) == 0) {
        unsigned long long pk = (unsigned long long)hv | ((unsigned long long)v1 << 16)
                              | ((unsigned long long)v2 << 32) | ((unsigned long long)v3 << 48);
        astore_u64((float*)(P.h16 + (size_t)wp * NBAT * HID + (size_t)bb * HID + bid * 8 + (jj & 4)), pk);
      }
      #pragma unroll
      for (int d = 0; d < 4; ++d)
        unsafeAtomicAdd(&fcp[bb * 4 + d], hreg * fcw[jj * 4 + d]);
    }
    __syncthreads();
    if (t < 256) unsafeAtomicAdd(&P.obg[((bid & 7) * 3 + wbuf) * 256 + t], fcp[t]);
    gbar(P.bar, target, xcc, leader);
  }

  // ---------------- epilogue ----------------
  if (bid == 0 && t < NBAT) {
    float4 acc = fcb;                            // out(63): wbuf at s=63 is 0
    #pragma unroll
    for (int g = 0; g < 8; ++g) {
      const float* pp = P.obg + (g * 3 + 0) * 256 + t * 4;
      float2 lo = aload_f32x2(pp), hi = aload_f32x2(pp + 2);
      acc.x += lo.x; acc.y += lo.y; acc.z += hi.x; acc.w += hi.y;
    }
    ((float4*)P.dst)[t * TDEC + 63] = acc;       // predictions[b][63]
    ((float4*)(P.dst + 16384))[t]   = acc;       // out
  }
  P.dst[16640  + (size_t)bb * HID + jglob] = hreg;   // h
  P.dst[147712 + (size_t)bb * HID + jglob] = creg;   // c
}

extern "C" void kernel_launch(void* const* d_in, const int* in_sizes, int n_in,
                              void* d_out, int out_size, void* d_ws, size_t ws_size,
                              hipStream_t stream) {
  (void)in_sizes; (void)n_in; (void)out_size; (void)ws_size;
  Params P;
  P.x        = (const float*)d_in[0];
  P.lengths  = (const int*)  d_in[1];
  // d_in[2] = target_len (constant 64)
  P.enc_Wih  = (const float*)d_in[3];
  P.enc_Whh  = (const float*)d_in[4];
  P.enc_bih  = (const float*)d_in[5];
  P.enc_bhh  = (const float*)d_in[6];
  P.emb_W    = (const float*)d_in[7];
  P.emb_b    = (const float*)d_in[8];
  P.dec_Wih  = (const float*)d_in[9];
  P.dec_Whh  = (const float*)d_in[10];
  P.dec_bih  = (const float*)d_in[11];
  P.dec_bhh  = (const float*)d_in[12];
  P.fc_W     = (const float*)d_in[13];
  P.fc_b     = (const float*)d_in[14];
  P.dst      = (float*)d_out;

  char* ws = (char*)d_ws;
  P.h16 = (f16*)ws;                                  // 2*64*2048*2 = 524288 B
  P.obg = (float*)(ws + 524288);                     // 8*3*256*4   =  24576 B
  P.bar = (unsigned*)(ws + 524288 + 24576);          //               12288 B

  hipMemsetAsync(P.bar, 0, 12288, stream);           // ws is poisoned 0xAA

  hipFuncSetAttribute((const void*)lstm_persistent,
                      hipFuncAttributeMaxDynamicSharedMemorySize, SMEM_BYTES);
  void* args[] = { &P };
  hipLaunchCooperativeKernel((const void*)lstm_persistent, dim3(NBLK), dim3(NTHR),
                             args, SMEM_BYTES, stream);
}